// Round 6
// baseline (6995.232 us; speedup 1.0000x reference)
//
#include <hip/hip_runtime.h>
#include <hip/hip_bf16.h>
#include <math.h>

typedef __hip_bfloat16 bf16;

#define BB 4
#define NN 1024
#define DD 1024
#define HH 16
#define KVH 4
#define HDIM 64
#define SS 128
#define CTXD 2048
#define MLPDIM 4096

__device__ __forceinline__ float bf2f(bf16 v){ return __bfloat162float(v); }
__device__ __forceinline__ bf16 f2bf(float v){ return __float2bfloat16(v); }
__device__ __forceinline__ float sigmf_(float x){ return 1.f/(1.f+expf(-x)); }
__device__ __forceinline__ float geluf_(float x){ return 0.5f*x*(1.f+erff(x*0.70710678118f)); }

// ---------- converts ----------
__global__ void k_copy(const float* __restrict__ in, float* __restrict__ out, int n){
  int i = blockIdx.x*256 + threadIdx.x;
  if (i < n) out[i] = in[i];
}
__global__ void k_f2bfv(const float* __restrict__ in, bf16* __restrict__ out, int n){
  int i = blockIdx.x*256 + threadIdx.x;
  if (i < n) out[i] = f2bf(in[i]);
}
__global__ void k_silu(const float* __restrict__ c, float* __restrict__ out, int n){
  int i = blockIdx.x*256 + threadIdx.x;
  if (i < n){ float v = c[i]; out[i] = v*sigmf_(v); }
}
__global__ void k_zero16(unsigned short* __restrict__ p, int n){
  int i = blockIdx.x*256 + threadIdx.x;
  if (i < n) p[i] = 0;
}

// ---------- adaLN: mod = silu(c) @ ada_w + ada_b   (B=4, K=1024, N=6144) ----------
__global__ void k_ada(const float* __restrict__ sc, const float* __restrict__ w,
                      const float* __restrict__ b, float* __restrict__ mod){
  int idx = blockIdx.x*256 + threadIdx.x;  // < 4*6144
  int bb = idx / 6144, col = idx % 6144;
  const float* cp = sc + bb*DD;
  float s = 0.f;
  for (int k = 0; k < DD; ++k) s += cp[k]*w[(size_t)k*6144 + col];
  mod[idx] = s + b[col];
}

// ---------- RMSNorm (+optional adaLN scale/shift). One block per row. ----------
__global__ __launch_bounds__(256) void k_rms(const float* __restrict__ X, const float* __restrict__ w,
                      const float* __restrict__ mod, int sc_off, int sh_off,
                      bf16* __restrict__ out, int use_mod){
  __shared__ float red[256];
  int row = blockIdx.x;            // 0..4095
  int b = row >> 10;
  int tid = threadIdx.x;
  const float* xr = X + (size_t)row*DD;
  float s = 0.f;
  #pragma unroll
  for (int i = 0; i < 4; ++i){ float v = xr[tid + i*256]; s += v*v; }
  red[tid] = s; __syncthreads();
  for (int st = 128; st > 0; st >>= 1){ if (tid < st) red[tid] += red[tid+st]; __syncthreads(); }
  float rstd = rsqrtf(red[0]*(1.f/DD) + 1e-6f);
  bf16* orow = out + (size_t)row*DD;
  const float* mrow = use_mod ? (mod + (size_t)b*6*DD) : nullptr;
  #pragma unroll
  for (int i = 0; i < 4; ++i){
    int d = tid + i*256;
    float v = xr[d]*rstd*w[d];
    if (use_mod) v = v*(1.f + mrow[sc_off + d]) + mrow[sh_off + d];
    orow[d] = f2bf(v);
  }
}

// ---------- generic GEMM: C(MxN,bf16) = A(MxK,bf16) @ Bw(KxN,fp32) [+bias][gelu], fp32 accum ----------
__global__ __launch_bounds__(256) void k_gemm(const bf16* __restrict__ A, const float* __restrict__ Bw,
                      const float* __restrict__ bias, bf16* __restrict__ C,
                      int M, int N, int K, int act){
  __shared__ float As[16][65];   // [kk][row]
  __shared__ float Bs[16][64];   // [kk][col]
  int tx = threadIdx.x, ty = threadIdx.y;
  int tid = ty*16 + tx;
  int bm = blockIdx.y*64, bn = blockIdx.x*64;
  float acc[4][4] = {};
  for (int k0 = 0; k0 < K; k0 += 16){
    #pragma unroll
    for (int i = 0; i < 4; ++i){
      int idx = tid + i*256;            // 0..1023
      int row = idx >> 4, kk = idx & 15;
      As[kk][row] = bf2f(A[(size_t)(bm+row)*K + k0 + kk]);
    }
    #pragma unroll
    for (int i = 0; i < 4; ++i){
      int idx = tid + i*256;
      int row = idx >> 6, col = idx & 63;
      Bs[row][col] = Bw[(size_t)(k0+row)*N + bn + col];
    }
    __syncthreads();
    #pragma unroll
    for (int kk = 0; kk < 16; ++kk){
      float a0[4], b0[4];
      #pragma unroll
      for (int i = 0; i < 4; ++i) a0[i] = As[kk][ty*4+i];
      #pragma unroll
      for (int j = 0; j < 4; ++j) b0[j] = Bs[kk][tx*4+j];
      #pragma unroll
      for (int i = 0; i < 4; ++i)
        #pragma unroll
        for (int j = 0; j < 4; ++j) acc[i][j] += a0[i]*b0[j];
    }
    __syncthreads();
  }
  #pragma unroll
  for (int i = 0; i < 4; ++i){
    size_t row = bm + ty*4 + i;
    #pragma unroll
    for (int j = 0; j < 4; ++j){
      int col = bn + tx*4 + j;
      float v = acc[i][j];
      if (bias) v += bias[col];
      if (act)  v = geluf_(v);
      C[row*N + col] = f2bf(v);
    }
  }
}

// ---------- RoPE: in (B,NN,NHp,64) -> out (B,NHp,NN,64), rotated ----------
__global__ void k_rope(const bf16* __restrict__ in, const float* __restrict__ cw,
                       const float* __restrict__ sw, bf16* __restrict__ out, int NHp, int n){
  int idx = blockIdx.x*256 + threadIdx.x;
  if (idx >= n) return;
  int d2 = idx & 31; int t = idx >> 5;
  int nn = t % NN; t /= NN; int h = t % NHp; int b = t / NHp;
  const bf16* base = in + ((size_t)((b*NN+nn)*NHp + h))*HDIM;
  float e = bf2f(base[2*d2]), o = bf2f(base[2*d2+1]);
  float c = cw[nn*32 + d2], s = sw[nn*32 + d2];
  bf16* ob = out + ((size_t)((b*NHp+h)*NN + nn))*HDIM;
  ob[d2]      = f2bf(e*c - o*s);
  ob[32 + d2] = f2bf(e*s + o*c);
}

// ---------- transpose (B,T,NHp,64) -> (B,NHp,T,64) ----------
__global__ void k_tr(const bf16* __restrict__ in, bf16* __restrict__ out, int T, int NHp, int n){
  int idx = blockIdx.x*256 + threadIdx.x;
  if (idx >= n) return;
  int d = idx & 63; int t = idx >> 6;
  int h = t % NHp; t /= NHp; int tok = t % T; int b = t / T;
  out[((size_t)((b*NHp+h)*T + tok))*64 + d] = in[idx];
}

// ---------- attention: one wave per (b,h,query) ----------
__global__ __launch_bounds__(64) void k_attn(const bf16* __restrict__ Q, const bf16* __restrict__ K,
                      const bf16* __restrict__ V, bf16* __restrict__ O,
                      int NH, int NKV, int Nq, int Nk, float scale){
  __shared__ float qs[64];
  __shared__ float sc[1024];
  int bid = blockIdx.x;
  int n = bid % Nq; int t = bid / Nq; int h = t % NH; int b = t / NH;
  int kvh = h / (NH / NKV);
  int lane = threadIdx.x;
  qs[lane] = bf2f(Q[((size_t)((b*NH+h)*Nq + n))*64 + lane]);
  __syncthreads();
  const bf16* Kb = K + ((size_t)(b*NKV+kvh))*Nk*64;
  float mx = -3.4e38f;
  for (int j = lane; j < Nk; j += 64){
    const bf16* kr = Kb + (size_t)j*64;
    float d = 0.f;
    #pragma unroll
    for (int dd = 0; dd < 64; ++dd) d += qs[dd]*bf2f(kr[dd]);
    d *= scale;
    sc[j] = d;
    mx = fmaxf(mx, d);
  }
  for (int off = 32; off; off >>= 1) mx = fmaxf(mx, __shfl_xor(mx, off, 64));
  float sum = 0.f;
  for (int j = lane; j < Nk; j += 64){
    float e = expf(sc[j] - mx);
    sc[j] = e; sum += e;
  }
  for (int off = 32; off; off >>= 1) sum += __shfl_xor(sum, off, 64);
  __syncthreads();
  float inv = 1.f/sum;
  const bf16* Vb = V + ((size_t)(b*NKV+kvh))*Nk*64;
  float acc = 0.f;
  for (int j = 0; j < Nk; ++j) acc += sc[j]*bf2f(Vb[(size_t)j*64 + lane]);
  O[((size_t)((b*Nq+n)*NH + h))*64 + lane] = f2bf(acc*inv);
}

// ---------- residual: X += (mod? g[b,d] : 1) * val ----------
__global__ void k_resid(float* __restrict__ X, const bf16* __restrict__ val,
                        const float* __restrict__ mod, int goff, int n){
  int i = blockIdx.x*256 + threadIdx.x;
  if (i >= n) return;
  float g = 1.f;
  if (mod){ int b = i >> 20; int d = i & 1023; g = mod[b*6144 + goff + d]; }
  X[i] += g*bf2f(val[i]);
}

// ---------- concat [X(fp32), VST(bf16)] -> CAT bf16 (rows of 2048) ----------
__global__ void k_concat(const float* __restrict__ X, const bf16* __restrict__ V,
                         bf16* __restrict__ C, int n){
  int i = blockIdx.x*256 + threadIdx.x;
  if (i >= n) return;
  int row = i >> 11, col = i & 2047;
  C[i] = (col < 1024) ? f2bf(X[(size_t)row*1024 + col]) : V[(size_t)row*1024 + col - 1024];
}

// ---------- integrator control update ----------
__global__ void k_ctrl(const bf16* __restrict__ ctrl, const float* __restrict__ X,
                       bf16* __restrict__ VST, bf16* __restrict__ XN,
                       const float* __restrict__ mu, int n){
  int i = blockIdx.x*256 + threadIdx.x;
  if (i >= n) return;
  int row = i >> 10, d = i & 1023;
  const bf16* cr = ctrl + (size_t)row*3072;
  float alpha = sigmf_(bf2f(cr[d]));
  float braw  = bf2f(cr[1024 + d]);
  float beta  = fmaxf(braw, 0.f) + log1pf(expf(-fabsf(braw)));
  float gate  = sigmf_(bf2f(cr[2048 + d]));
  float vn = alpha*bf2f(VST[i]) - beta*(X[i] - mu[d]);
  VST[i] = f2bf(vn);
  XN[i]  = f2bf(X[i] + 0.1f*gate*vn);
}

// ---------- hg2: hp = sigmoid(hg1out @ w + b) ; fp32 halt tail ----------
__global__ __launch_bounds__(64) void k_hg2(const bf16* __restrict__ hin, const float* __restrict__ w,
                     const float* __restrict__ bb, float* __restrict__ hp,
                     float* __restrict__ oout, int it){
  int r = blockIdx.x; int lane = threadIdx.x;
  const bf16* hr = hin + (size_t)r*256;
  float s = 0.f;
  #pragma unroll
  for (int i = 0; i < 4; ++i) s += bf2f(hr[lane + i*64])*w[lane + i*64];
  for (int off = 32; off; off >>= 1) s += __shfl_xor(s, off, 64);
  if (lane == 0){
    float v = sigmf_(s + bb[0]);
    hp[r] = v;
    int b = r >> 10, nn = r & 1023;
    oout[((size_t)(b*2 + it) << 10) + nn] = v;
  }
}

// ---------- integ += hp * refined * int_w ----------
__global__ void k_integ(float* __restrict__ X, const float* __restrict__ hp,
                        const bf16* __restrict__ rf, const float* __restrict__ iw, int n){
  int i = blockIdx.x*256 + threadIdx.x;
  if (i >= n) return;
  int row = i >> 10, d = i & 1023;
  X[i] += hp[row]*bf2f(rf[i])*iw[d];
}

extern "C" void kernel_launch(void* const* d_in, const int* in_sizes, int n_in,
                              void* d_out, int out_size, void* d_ws, size_t ws_size,
                              hipStream_t stream) {
  const float* x_in  = (const float*)d_in[0];
  const float* c_in  = (const float*)d_in[1];
  const float* ctx_in= (const float*)d_in[2];
  const float* cosw  = (const float*)d_in[3];
  const float* sinw  = (const float*)d_in[4];
  const float* wq    = (const float*)d_in[5];
  const float* wk    = (const float*)d_in[6];
  const float* wv    = (const float*)d_in[7];
  const float* wo    = (const float*)d_in[8];
  const float* cwq   = (const float*)d_in[9];
  const float* cwk   = (const float*)d_in[10];
  const float* cwv   = (const float*)d_in[11];
  const float* cwo   = (const float*)d_in[12];
  const float* fc1_w = (const float*)d_in[13];
  const float* fc1_b = (const float*)d_in[14];
  const float* fc2_w = (const float*)d_in[15];
  const float* fc2_b = (const float*)d_in[16];
  const float* ada_w = (const float*)d_in[17];
  const float* ada_b = (const float*)d_in[18];
  const float* n1    = (const float*)d_in[19];
  const float* n2    = (const float*)d_in[20];
  const float* n3    = (const float*)d_in[21];
  const float* int_w = (const float*)d_in[22];
  const float* mu    = (const float*)d_in[23];
  const float* hg1_w = (const float*)d_in[24];
  const float* hg1_b = (const float*)d_in[25];
  const float* hg2_w = (const float*)d_in[26];
  const float* hg2_b = (const float*)d_in[27];
  const float* ct1_w = (const float*)d_in[28];
  const float* ct1_b = (const float*)d_in[29];
  const float* ct2_w = (const float*)d_in[30];
  const float* ct2_b = (const float*)d_in[31];
  const float* rf1_w = (const float*)d_in[32];
  const float* rf1_b = (const float*)d_in[33];
  const float* rf2_w = (const float*)d_in[34];
  const float* rf2_b = (const float*)d_in[35];

  float* out_f  = (float*)d_out;                 // fp32 output (confirmed r5)
  float* out_hp = out_f + (size_t)BB*NN*DD;      // halt-prob tail (B,2,N,1) fp32

  // ---- workspace map (~64.2 MB; ws_size >= 68MB confirmed r5) ----
  char* wsb = (char*)d_ws;
  const size_t Mi = 1u << 20;
  float* X  = (float*)wsb;                    // [0,16MB)  4M fp32, persistent x/integ
  bf16*  Hh = (bf16*)(wsb + 16*Mi);           // [16,24MB) h/h2/h3; XN in integrator
  bf16*  Qb = (bf16*)(wsb + 24*Mi);           // [24,32MB) q-proj/fc2out; VST in integrator
  bf16*  R  = (bf16*)(wsb + 32*Mi);           // [32,64MB) 16M bf16 shared region
  bf16*  QR  = R;                             // R[0:4M]
  bf16*  SAb = R + 4*Mi;                      // R[4M:8M]
  bf16*  KP  = R + 8*Mi;
  bf16*  VP  = R + 9*Mi;
  bf16*  KR  = R + 10*Mi;
  bf16*  VR  = R + 11*Mi;
  bf16*  CTXB= R + 12*Mi;
  bf16*  BIG = R;                             // R[0:16M]
  bf16*  CT1 = R + 12*Mi;                     // R[12M:14M]
  bf16*  HG1 = R + 12*Mi;                     // R[12M:13M]
  bf16*  RFO = R + 8*Mi;                      // R[8M:12M]
  float* SIL = (float*)(wsb + 64*Mi);         // 4096
  float* MOD = SIL + 4096;                    // 24576
  float* HP  = MOD + 24576;                   // 4096
  bf16*  VST = Qb;
  bf16*  XN  = Hh;

  const int NT = BB*NN*DD;
  const float scale = 0.125f;
  dim3 tb(16,16);
  #define G1(n) dim3(((n)+255)/256), dim3(256)

  // x -> X (fp32); mod = silu(c) @ ada_w + ada_b
  k_copy<<<G1(NT), 0, stream>>>(x_in, X, NT);
  k_silu<<<G1(BB*DD), 0, stream>>>(c_in, SIL, BB*DD);
  k_ada<<<dim3(96), dim3(256), 0, stream>>>(SIL, ada_w, ada_b, MOD);

  // ---- self-attention ----
  k_rms<<<dim3(4096), dim3(256), 0, stream>>>(X, n1, MOD, DD, 0, Hh, 1);
  k_gemm<<<dim3(16,64), tb, 0, stream>>>(Hh, wq, nullptr, Qb, 4096, 1024, 1024, 0);
  k_gemm<<<dim3(4,64),  tb, 0, stream>>>(Hh, wk, nullptr, KP, 4096, 256, 1024, 0);
  k_gemm<<<dim3(4,64),  tb, 0, stream>>>(Hh, wv, nullptr, VP, 4096, 256, 1024, 0);
  k_rope<<<G1(BB*HH*NN*32), 0, stream>>>(Qb, cosw, sinw, QR, HH, BB*HH*NN*32);
  k_rope<<<G1(BB*KVH*NN*32), 0, stream>>>(KP, cosw, sinw, KR, KVH, BB*KVH*NN*32);
  k_tr<<<G1(BB*NN*KVH*64), 0, stream>>>(VP, VR, NN, KVH, BB*NN*KVH*64);
  k_attn<<<dim3(BB*HH*NN), dim3(64), 0, stream>>>(QR, KR, VR, SAb, HH, KVH, NN, NN, scale);
  k_gemm<<<dim3(16,64), tb, 0, stream>>>(SAb, wo, nullptr, Hh, 4096, 1024, 1024, 0);
  k_resid<<<G1(NT), 0, stream>>>(X, Hh, MOD, 2*DD, NT);

  // ---- cross-attention ----
  k_rms<<<dim3(4096), dim3(256), 0, stream>>>(X, n2, nullptr, 0, 0, Hh, 0);
  k_gemm<<<dim3(16,64), tb, 0, stream>>>(Hh, cwq, nullptr, Qb, 4096, 1024, 1024, 0);
  k_tr<<<G1(NT), 0, stream>>>(Qb, QR, NN, HH, NT);
  k_f2bfv<<<G1(BB*SS*CTXD), 0, stream>>>(ctx_in, CTXB, BB*SS*CTXD);
  k_gemm<<<dim3(16,8), tb, 0, stream>>>(CTXB, cwk, nullptr, KP, 512, 1024, 2048, 0);
  k_gemm<<<dim3(16,8), tb, 0, stream>>>(CTXB, cwv, nullptr, VP, 512, 1024, 2048, 0);
  k_tr<<<G1(BB*SS*HH*64), 0, stream>>>(KP, KR, SS, HH, BB*SS*HH*64);
  k_tr<<<G1(BB*SS*HH*64), 0, stream>>>(VP, VR, SS, HH, BB*SS*HH*64);
  k_attn<<<dim3(BB*HH*NN), dim3(64), 0, stream>>>(QR, KR, VR, SAb, HH, HH, NN, SS, scale);
  k_gemm<<<dim3(16,64), tb, 0, stream>>>(SAb, cwo, nullptr, Hh, 4096, 1024, 1024, 0);
  k_resid<<<G1(NT), 0, stream>>>(X, Hh, nullptr, 0, NT);

  // ---- MLP ----
  k_rms<<<dim3(4096), dim3(256), 0, stream>>>(X, n3, MOD, 4*DD, 3*DD, Hh, 1);
  k_gemm<<<dim3(64,64), tb, 0, stream>>>(Hh, fc1_w, fc1_b, BIG, 4096, 4096, 1024, 1);
  k_gemm<<<dim3(16,64), tb, 0, stream>>>(BIG, fc2_w, fc2_b, Qb, 4096, 1024, 4096, 0);
  k_resid<<<G1(NT), 0, stream>>>(X, Qb, MOD, 5*DD, NT);

  // ---- integrator (NITER=2) ----
  k_zero16<<<G1(NT), 0, stream>>>((unsigned short*)VST, NT);
  for (int it = 0; it < 2; ++it){
    k_concat<<<G1(2*NT), 0, stream>>>(X, VST, BIG, 2*NT);
    k_gemm<<<dim3(8,64),  tb, 0, stream>>>(BIG, ct1_w, ct1_b, CT1, 4096, 512, 2048, 1);
    k_gemm<<<dim3(48,64), tb, 0, stream>>>(CT1, ct2_w, ct2_b, BIG, 4096, 3072, 512, 0);
    k_ctrl<<<G1(NT), 0, stream>>>(BIG, X, VST, XN, mu, NT);
    k_gemm<<<dim3(4,64),  tb, 0, stream>>>(XN, hg1_w, hg1_b, HG1, 4096, 256, 1024, 1);
    k_hg2<<<dim3(4096), dim3(64), 0, stream>>>(HG1, hg2_w, hg2_b, HP, out_hp, it);
    k_gemm<<<dim3(32,64), tb, 0, stream>>>(XN, rf1_w, rf1_b, BIG, 4096, 2048, 1024, 1);
    k_gemm<<<dim3(16,64), tb, 0, stream>>>(BIG, rf2_w, rf2_b, RFO, 4096, 1024, 2048, 0);
    k_integ<<<G1(NT), 0, stream>>>(X, HP, RFO, int_w, NT);
  }
  // ---- final output: FP32 ----
  k_copy<<<G1(NT), 0, stream>>>(X, out_f, NT);
  #undef G1
}

// Round 7
// 2529.383 us; speedup vs baseline: 2.7656x; 2.7656x over previous
//
#include <hip/hip_runtime.h>
#include <hip/hip_bf16.h>
#include <math.h>

typedef __hip_bfloat16 bf16;
typedef unsigned short ushort;
typedef __bf16 bf16x8 __attribute__((ext_vector_type(8)));
typedef unsigned short u16x8 __attribute__((ext_vector_type(8)));
typedef float f32x4 __attribute__((ext_vector_type(4)));

#define BB 4
#define NN 1024
#define DD 1024
#define HH 16
#define KVH 4
#define HDIM 64
#define SS 128
#define CTXD 2048
#define MLPDIM 4096

__device__ __forceinline__ float bf2f(bf16 v){ return __bfloat162float(v); }
__device__ __forceinline__ bf16 f2bf(float v){ return __float2bfloat16(v); }
__device__ __forceinline__ ushort fbits(float v){ bf16 h = __float2bfloat16(v); return *(ushort*)&h; }
__device__ __forceinline__ float ubf(ushort u){ unsigned int x = ((unsigned int)u) << 16; float f; *(unsigned int*)&f = x; return f; }
__device__ __forceinline__ float sigmf_(float x){ return 1.f/(1.f+expf(-x)); }
__device__ __forceinline__ float geluf_(float x){ return 0.5f*x*(1.f+erff(x*0.70710678118f)); }

// ---------- converts ----------
__global__ void k_copy4(const float4* __restrict__ in, float4* __restrict__ out, int n4){
  int i = blockIdx.x*256 + threadIdx.x;
  if (i < n4) out[i] = in[i];
}
__global__ void k_f2bfv(const float* __restrict__ in, bf16* __restrict__ out, int n){
  int i = blockIdx.x*256 + threadIdx.x;
  if (i < n) out[i] = f2bf(in[i]);
}
__global__ void k_silu(const float* __restrict__ c, float* __restrict__ out, int n){
  int i = blockIdx.x*256 + threadIdx.x;
  if (i < n){ float v = c[i]; out[i] = v*sigmf_(v); }
}
__global__ void k_zero16(unsigned short* __restrict__ p, int n){
  int i = blockIdx.x*256 + threadIdx.x;
  if (i < n) p[i] = 0;
}

// ---------- adaLN: mod = silu(c) @ ada_w + ada_b ----------
__global__ void k_ada(const float* __restrict__ sc, const float* __restrict__ w,
                      const float* __restrict__ b, float* __restrict__ mod){
  int idx = blockIdx.x*256 + threadIdx.x;  // < 4*6144
  int bb = idx / 6144, col = idx % 6144;
  const float* cp = sc + bb*DD;
  float s = 0.f;
  for (int k = 0; k < DD; ++k) s += cp[k]*w[(size_t)k*6144 + col];
  mod[idx] = s + b[col];
}

// ---------- RMSNorm (+optional adaLN scale/shift) ----------
__global__ __launch_bounds__(256) void k_rms(const float* __restrict__ X, const float* __restrict__ w,
                      const float* __restrict__ mod, int sc_off, int sh_off,
                      bf16* __restrict__ out, int use_mod){
  __shared__ float red[256];
  int row = blockIdx.x;
  int b = row >> 10;
  int tid = threadIdx.x;
  const float* xr = X + (size_t)row*DD;
  float s = 0.f;
  #pragma unroll
  for (int i = 0; i < 4; ++i){ float v = xr[tid + i*256]; s += v*v; }
  red[tid] = s; __syncthreads();
  for (int st = 128; st > 0; st >>= 1){ if (tid < st) red[tid] += red[tid+st]; __syncthreads(); }
  float rstd = rsqrtf(red[0]*(1.f/DD) + 1e-6f);
  bf16* orow = out + (size_t)row*DD;
  const float* mrow = use_mod ? (mod + (size_t)b*6*DD) : nullptr;
  #pragma unroll
  for (int i = 0; i < 4; ++i){
    int d = tid + i*256;
    float v = xr[d]*rstd*w[d];
    if (use_mod) v = v*(1.f + mrow[sc_off + d]) + mrow[sh_off + d];
    orow[d] = f2bf(v);
  }
}

// ---------- MFMA GEMM: C(MxN,bf16) = A(MxK,bf16) @ Bw(KxN,fp32) [+bias][gelu] ----------
// M%128==0, N%128==0, K%32==0. Block 256 = 4 waves, each wave 64x64 (4x4 MFMA 16x16x32).
__global__ __launch_bounds__(256,2) void k_mm(const ushort* __restrict__ A, const float* __restrict__ Bw,
                      const float* __restrict__ bias, ushort* __restrict__ C,
                      int M, int N, int K, int act){
  __shared__ ushort As[128*40];   // [m][k] rows padded to 40 (80B, 16B-aligned, 2-way banks)
  __shared__ ushort Bs[32*132];   // [k][n] rows padded to 132 (264B, 2-way banks on frag reads)
  int tid = threadIdx.x, lane = tid & 63, wv = tid >> 6;
  int l15 = lane & 15, quad = lane >> 4;
  int bm = blockIdx.y*128, bn = blockIdx.x*128;
  int wm = (wv & 1)*64, wn = (wv >> 1)*64;
  f32x4 acc[4][4] = {};
  for (int k0 = 0; k0 < K; k0 += 32){
    // stage A: 128x32 bf16, thread loads 2 chunks of 8
    #pragma unroll
    for (int i = 0; i < 2; ++i){
      int c = tid + i*256; int row = c >> 2; int k8 = (c & 3) << 3;
      uint4 v = *(const uint4*)(A + (size_t)(bm+row)*K + k0 + k8);
      *(uint4*)(As + row*40 + k8) = v;
    }
    // stage B: 32x128 fp32 -> bf16, thread loads 4 chunks of 4
    #pragma unroll
    for (int i = 0; i < 4; ++i){
      int c = tid + i*256; int kk = c >> 5; int n4 = (c & 31) << 2;
      float4 v = *(const float4*)(Bw + (size_t)(k0+kk)*N + bn + n4);
      uint2 pk;
      pk.x = (unsigned int)fbits(v.x) | ((unsigned int)fbits(v.y) << 16);
      pk.y = (unsigned int)fbits(v.z) | ((unsigned int)fbits(v.w) << 16);
      *(uint2*)(Bs + kk*132 + n4) = pk;
    }
    __syncthreads();
    bf16x8 af[4], bfr[4];
    #pragma unroll
    for (int mi = 0; mi < 4; ++mi){
      uint4 v = *(const uint4*)(As + (wm + mi*16 + l15)*40 + quad*8);
      af[mi] = __builtin_bit_cast(bf16x8, v);
    }
    #pragma unroll
    for (int nj = 0; nj < 4; ++nj){
      int col = wn + nj*16 + l15;
      u16x8 ev;
      #pragma unroll
      for (int j = 0; j < 8; ++j) ev[j] = Bs[(quad*8 + j)*132 + col];
      bfr[nj] = __builtin_bit_cast(bf16x8, ev);
    }
    #pragma unroll
    for (int mi = 0; mi < 4; ++mi)
      #pragma unroll
      for (int nj = 0; nj < 4; ++nj)
        acc[mi][nj] = __builtin_amdgcn_mfma_f32_16x16x32_bf16(af[mi], bfr[nj], acc[mi][nj], 0, 0, 0);
    __syncthreads();
  }
  // epilogue: C/D layout col=lane&15, row=quad*4+r
  #pragma unroll
  for (int nj = 0; nj < 4; ++nj){
    int col = bn + wn + nj*16 + l15;
    float bv = bias ? bias[col] : 0.f;
    #pragma unroll
    for (int mi = 0; mi < 4; ++mi){
      #pragma unroll
      for (int r = 0; r < 4; ++r){
        int row = bm + wm + mi*16 + quad*4 + r;
        float v = acc[mi][nj][r] + bv;
        if (act) v = geluf_(v);
        C[(size_t)row*N + col] = fbits(v);
      }
    }
  }
}

// ---------- RoPE: in (B,NN,NHp,64) -> out (B,NHp,NN,64), rotated ----------
__global__ void k_rope(const bf16* __restrict__ in, const float* __restrict__ cw,
                       const float* __restrict__ sw, bf16* __restrict__ out, int NHp, int n){
  int idx = blockIdx.x*256 + threadIdx.x;
  if (idx >= n) return;
  int d2 = idx & 31; int t = idx >> 5;
  int nn = t % NN; t /= NN; int h = t % NHp; int b = t / NHp;
  const bf16* base = in + ((size_t)((b*NN+nn)*NHp + h))*HDIM;
  float e = bf2f(base[2*d2]), o = bf2f(base[2*d2+1]);
  float c = cw[nn*32 + d2], s = sw[nn*32 + d2];
  bf16* ob = out + ((size_t)((b*NHp+h)*NN + nn))*HDIM;
  ob[d2]      = f2bf(e*c - o*s);
  ob[32 + d2] = f2bf(e*s + o*c);
}

// ---------- transpose (B,T,NHp,64) -> (B,NHp,T,64) ----------
__global__ void k_tr(const bf16* __restrict__ in, bf16* __restrict__ out, int T, int NHp, int n){
  int idx = blockIdx.x*256 + threadIdx.x;
  if (idx >= n) return;
  int d = idx & 63; int t = idx >> 6;
  int h = t % NHp; t /= NHp; int tok = t % T; int b = t / T;
  out[((size_t)((b*NHp+h)*T + tok))*64 + d] = in[idx];
}

// ---------- flash attention: block = 4 waves = 4 queries of one (b,h); K/V LDS tiles of 128 ----------
__global__ __launch_bounds__(256) void k_fattn(const ushort* __restrict__ Q, const ushort* __restrict__ K,
                      const ushort* __restrict__ V, ushort* __restrict__ O,
                      int NH, int NKV, int Nq, int Nk, float scale){
  __shared__ ushort Kt[128*66];   // [j][k], stride 66 -> QK reads 2-way (free)
  __shared__ ushort Vt[128*64];   // [j][d], PV reads conflict-free
  __shared__ float qs[4][64];
  __shared__ float ps[4][128];
  int tid = threadIdx.x, lane = tid & 63, wv = tid >> 6;
  int nq4 = Nq >> 2;
  int q4 = blockIdx.x % nq4; int t = blockIdx.x / nq4; int h = t % NH; int b = t / NH;
  int kvh = h / (NH / NKV);
  int n = q4*4 + wv;
  qs[wv][lane] = ubf(Q[((size_t)((b*NH+h)*Nq + n))*64 + lane]);
  float m_run = -1e30f, l_run = 0.f, accd = 0.f;
  const ushort* Kb = K + (size_t)(b*NKV+kvh)*Nk*64;
  const ushort* Vb = V + (size_t)(b*NKV+kvh)*Nk*64;
  for (int t0 = 0; t0 < Nk; t0 += 128){
    // stage 128 rows of K and V (64 bf16 each)
    #pragma unroll
    for (int i = 0; i < 4; ++i){
      int c = tid + i*256; int row = c >> 3; int k8 = (c & 7) << 3;
      uint4 kv = *(const uint4*)(Kb + (size_t)(t0+row)*64 + k8);
      ushort* kd = Kt + row*66 + k8;
      *(uint*)(kd+0) = kv.x; *(uint*)(kd+2) = kv.y; *(uint*)(kd+4) = kv.z; *(uint*)(kd+6) = kv.w;
      uint4 vv = *(const uint4*)(Vb + (size_t)(t0+row)*64 + k8);
      *(uint4*)(Vt + row*64 + k8) = vv;
    }
    __syncthreads();
    // scores for rows j=lane, lane+64
    const float* qw = qs[wv];
    const ushort* kr0 = Kt + lane*66;
    const ushort* kr1 = Kt + (lane+64)*66;
    float s0 = 0.f, s1 = 0.f;
    #pragma unroll 8
    for (int k = 0; k < 64; ++k){
      float qv = qw[k];
      s0 += qv*ubf(kr0[k]);
      s1 += qv*ubf(kr1[k]);
    }
    s0 *= scale; s1 *= scale;
    float tmax = fmaxf(s0, s1);
    for (int off = 32; off; off >>= 1) tmax = fmaxf(tmax, __shfl_xor(tmax, off, 64));
    float m_new = fmaxf(m_run, tmax);
    float alpha = expf(m_run - m_new);
    float p0 = expf(s0 - m_new), p1 = expf(s1 - m_new);
    float tsum = p0 + p1;
    for (int off = 32; off; off >>= 1) tsum += __shfl_xor(tsum, off, 64);
    l_run = l_run*alpha + tsum;
    m_run = m_new;
    ps[wv][lane] = p0; ps[wv][lane+64] = p1;
    __syncthreads();
    accd *= alpha;
    const float* pw = ps[wv];
    float t0a = 0.f, t1a = 0.f, t2a = 0.f, t3a = 0.f;
    for (int j = 0; j < 128; j += 4){
      t0a += pw[j+0]*ubf(Vt[(j+0)*64 + lane]);
      t1a += pw[j+1]*ubf(Vt[(j+1)*64 + lane]);
      t2a += pw[j+2]*ubf(Vt[(j+2)*64 + lane]);
      t3a += pw[j+3]*ubf(Vt[(j+3)*64 + lane]);
    }
    accd += (t0a+t1a) + (t2a+t3a);
    __syncthreads();
  }
  float o = accd / l_run;
  O[((size_t)((b*Nq+n)*NH + h))*64 + lane] = fbits(o);
}

// ---------- residual: X += (mod? g[b,d] : 1) * val ----------
__global__ void k_resid(float* __restrict__ X, const bf16* __restrict__ val,
                        const float* __restrict__ mod, int goff, int n){
  int i = blockIdx.x*256 + threadIdx.x;
  if (i >= n) return;
  float g = 1.f;
  if (mod){ int b = i >> 20; int d = i & 1023; g = mod[b*6144 + goff + d]; }
  X[i] += g*bf2f(val[i]);
}

// ---------- concat [X(fp32), VST(bf16)] -> CAT bf16 ----------
__global__ void k_concat(const float* __restrict__ X, const bf16* __restrict__ V,
                         bf16* __restrict__ C, int n){
  int i = blockIdx.x*256 + threadIdx.x;
  if (i >= n) return;
  int row = i >> 11, col = i & 2047;
  C[i] = (col < 1024) ? f2bf(X[(size_t)row*1024 + col]) : V[(size_t)row*1024 + col - 1024];
}

// ---------- integrator control update ----------
__global__ void k_ctrl(const bf16* __restrict__ ctrl, const float* __restrict__ X,
                       bf16* __restrict__ VST, bf16* __restrict__ XN,
                       const float* __restrict__ mu, int n){
  int i = blockIdx.x*256 + threadIdx.x;
  if (i >= n) return;
  int row = i >> 10, d = i & 1023;
  const bf16* cr = ctrl + (size_t)row*3072;
  float alpha = sigmf_(bf2f(cr[d]));
  float braw  = bf2f(cr[1024 + d]);
  float beta  = fmaxf(braw, 0.f) + log1pf(expf(-fabsf(braw)));
  float gate  = sigmf_(bf2f(cr[2048 + d]));
  float vn = alpha*bf2f(VST[i]) - beta*(X[i] - mu[d]);
  VST[i] = f2bf(vn);
  XN[i]  = f2bf(X[i] + 0.1f*gate*vn);
}

// ---------- hg2: hp = sigmoid(hg1out @ w + b) ; fp32 halt tail ----------
__global__ __launch_bounds__(64) void k_hg2(const bf16* __restrict__ hin, const float* __restrict__ w,
                     const float* __restrict__ bb, float* __restrict__ hp,
                     float* __restrict__ oout, int it){
  int r = blockIdx.x; int lane = threadIdx.x;
  const bf16* hr = hin + (size_t)r*256;
  float s = 0.f;
  #pragma unroll
  for (int i = 0; i < 4; ++i) s += bf2f(hr[lane + i*64])*w[lane + i*64];
  for (int off = 32; off; off >>= 1) s += __shfl_xor(s, off, 64);
  if (lane == 0){
    float v = sigmf_(s + bb[0]);
    hp[r] = v;
    int b = r >> 10, nn = r & 1023;
    oout[((size_t)(b*2 + it) << 10) + nn] = v;
  }
}

// ---------- integ += hp * refined * int_w ----------
__global__ void k_integ(float* __restrict__ X, const float* __restrict__ hp,
                        const bf16* __restrict__ rf, const float* __restrict__ iw, int n){
  int i = blockIdx.x*256 + threadIdx.x;
  if (i >= n) return;
  int row = i >> 10, d = i & 1023;
  X[i] += hp[row]*bf2f(rf[i])*iw[d];
}

extern "C" void kernel_launch(void* const* d_in, const int* in_sizes, int n_in,
                              void* d_out, int out_size, void* d_ws, size_t ws_size,
                              hipStream_t stream) {
  const float* x_in  = (const float*)d_in[0];
  const float* c_in  = (const float*)d_in[1];
  const float* ctx_in= (const float*)d_in[2];
  const float* cosw  = (const float*)d_in[3];
  const float* sinw  = (const float*)d_in[4];
  const float* wq    = (const float*)d_in[5];
  const float* wk    = (const float*)d_in[6];
  const float* wv    = (const float*)d_in[7];
  const float* wo    = (const float*)d_in[8];
  const float* cwq   = (const float*)d_in[9];
  const float* cwk   = (const float*)d_in[10];
  const float* cwv   = (const float*)d_in[11];
  const float* cwo   = (const float*)d_in[12];
  const float* fc1_w = (const float*)d_in[13];
  const float* fc1_b = (const float*)d_in[14];
  const float* fc2_w = (const float*)d_in[15];
  const float* fc2_b = (const float*)d_in[16];
  const float* ada_w = (const float*)d_in[17];
  const float* ada_b = (const float*)d_in[18];
  const float* n1    = (const float*)d_in[19];
  const float* n2    = (const float*)d_in[20];
  const float* n3    = (const float*)d_in[21];
  const float* int_w = (const float*)d_in[22];
  const float* mu    = (const float*)d_in[23];
  const float* hg1_w = (const float*)d_in[24];
  const float* hg1_b = (const float*)d_in[25];
  const float* hg2_w = (const float*)d_in[26];
  const float* hg2_b = (const float*)d_in[27];
  const float* ct1_w = (const float*)d_in[28];
  const float* ct1_b = (const float*)d_in[29];
  const float* ct2_w = (const float*)d_in[30];
  const float* ct2_b = (const float*)d_in[31];
  const float* rf1_w = (const float*)d_in[32];
  const float* rf1_b = (const float*)d_in[33];
  const float* rf2_w = (const float*)d_in[34];
  const float* rf2_b = (const float*)d_in[35];

  float* out_f  = (float*)d_out;
  float* out_hp = out_f + (size_t)BB*NN*DD;

  // ---- workspace map (~64.2 MB) ----
  char* wsb = (char*)d_ws;
  const size_t Mi = 1u << 20;
  float* X  = (float*)wsb;                    // [0,16MB)
  bf16*  Hh = (bf16*)(wsb + 16*Mi);           // [16,24MB)
  bf16*  Qb = (bf16*)(wsb + 24*Mi);           // [24,32MB)
  bf16*  R  = (bf16*)(wsb + 32*Mi);           // [32,64MB)
  bf16*  QR  = R;
  bf16*  SAb = R + 4*Mi;
  bf16*  KP  = R + 8*Mi;
  bf16*  VP  = R + 9*Mi;
  bf16*  KR  = R + 10*Mi;
  bf16*  VR  = R + 11*Mi;
  bf16*  CTXB= R + 12*Mi;
  bf16*  BIG = R;
  bf16*  CT1 = R + 12*Mi;
  bf16*  HG1 = R + 12*Mi;
  bf16*  RFO = R + 8*Mi;
  float* SIL = (float*)(wsb + 64*Mi);
  float* MOD = SIL + 4096;
  float* HP  = MOD + 24576;
  bf16*  VST = Qb;
  bf16*  XN  = Hh;

  const int NT = BB*NN*DD;
  const float scale = 0.125f;
  #define G1(n) dim3(((n)+255)/256), dim3(256)
  #define MM(Aptr,Bptr,biasptr,Cptr,M,N,K,act) \
    k_mm<<<dim3((N)/128,(M)/128), dim3(256), 0, stream>>>((const ushort*)(Aptr),(Bptr),(biasptr),(ushort*)(Cptr),(M),(N),(K),(act))

  // x -> X; mod = silu(c) @ ada_w + ada_b
  k_copy4<<<G1(NT/4), 0, stream>>>((const float4*)x_in, (float4*)X, NT/4);
  k_silu<<<G1(BB*DD), 0, stream>>>(c_in, SIL, BB*DD);
  k_ada<<<dim3(96), dim3(256), 0, stream>>>(SIL, ada_w, ada_b, MOD);

  // ---- self-attention ----
  k_rms<<<dim3(4096), dim3(256), 0, stream>>>(X, n1, MOD, DD, 0, Hh, 1);
  MM(Hh, wq, nullptr, Qb, 4096, 1024, 1024, 0);
  MM(Hh, wk, nullptr, KP, 4096, 256, 1024, 0);
  MM(Hh, wv, nullptr, VP, 4096, 256, 1024, 0);
  k_rope<<<G1(BB*HH*NN*32), 0, stream>>>(Qb, cosw, sinw, QR, HH, BB*HH*NN*32);
  k_rope<<<G1(BB*KVH*NN*32), 0, stream>>>(KP, cosw, sinw, KR, KVH, BB*KVH*NN*32);
  k_tr<<<G1(BB*NN*KVH*64), 0, stream>>>(VP, VR, NN, KVH, BB*NN*KVH*64);
  k_fattn<<<dim3(BB*HH*(NN/4)), dim3(256), 0, stream>>>((const ushort*)QR, (const ushort*)KR,
      (const ushort*)VR, (ushort*)SAb, HH, KVH, NN, NN, scale);
  MM(SAb, wo, nullptr, Hh, 4096, 1024, 1024, 0);
  k_resid<<<G1(NT), 0, stream>>>(X, Hh, MOD, 2*DD, NT);

  // ---- cross-attention ----
  k_rms<<<dim3(4096), dim3(256), 0, stream>>>(X, n2, nullptr, 0, 0, Hh, 0);
  MM(Hh, cwq, nullptr, Qb, 4096, 1024, 1024, 0);
  k_tr<<<G1(NT), 0, stream>>>(Qb, QR, NN, HH, NT);
  k_f2bfv<<<G1(BB*SS*CTXD), 0, stream>>>(ctx_in, CTXB, BB*SS*CTXD);
  MM(CTXB, cwk, nullptr, KP, 512, 1024, 2048, 0);
  MM(CTXB, cwv, nullptr, VP, 512, 1024, 2048, 0);
  k_tr<<<G1(BB*SS*HH*64), 0, stream>>>(KP, KR, SS, HH, BB*SS*HH*64);
  k_tr<<<G1(BB*SS*HH*64), 0, stream>>>(VP, VR, SS, HH, BB*SS*HH*64);
  k_fattn<<<dim3(BB*HH*(NN/4)), dim3(256), 0, stream>>>((const ushort*)QR, (const ushort*)KR,
      (const ushort*)VR, (ushort*)SAb, HH, HH, NN, SS, scale);
  MM(SAb, cwo, nullptr, Hh, 4096, 1024, 1024, 0);
  k_resid<<<G1(NT), 0, stream>>>(X, Hh, nullptr, 0, NT);

  // ---- MLP ----
  k_rms<<<dim3(4096), dim3(256), 0, stream>>>(X, n3, MOD, 4*DD, 3*DD, Hh, 1);
  MM(Hh, fc1_w, fc1_b, BIG, 4096, 4096, 1024, 1);
  MM(BIG, fc2_w, fc2_b, Qb, 4096, 1024, 4096, 0);
  k_resid<<<G1(NT), 0, stream>>>(X, Qb, MOD, 5*DD, NT);

  // ---- integrator (NITER=2) ----
  k_zero16<<<G1(NT), 0, stream>>>((unsigned short*)VST, NT);
  for (int it = 0; it < 2; ++it){
    k_concat<<<G1(2*NT), 0, stream>>>(X, VST, BIG, 2*NT);
    MM(BIG, ct1_w, ct1_b, CT1, 4096, 512, 2048, 1);
    MM(CT1, ct2_w, ct2_b, BIG, 4096, 3072, 512, 0);
    k_ctrl<<<G1(NT), 0, stream>>>(BIG, X, VST, XN, mu, NT);
    MM(XN, hg1_w, hg1_b, HG1, 4096, 256, 1024, 1);
    k_hg2<<<dim3(4096), dim3(64), 0, stream>>>(HG1, hg2_w, hg2_b, HP, out_hp, it);
    MM(XN, rf1_w, rf1_b, BIG, 4096, 2048, 1024, 1);
    MM(BIG, rf2_w, rf2_b, RFO, 4096, 1024, 2048, 0);
    k_integ<<<G1(NT), 0, stream>>>(X, HP, RFO, int_w, NT);
  }
  // ---- final output: FP32 ----
  k_copy4<<<G1(NT/4), 0, stream>>>((const float4*)X, (float4*)out_f, NT/4);
  #undef G1
  #undef MM
}